// Round 1
// baseline (497.531 us; speedup 1.0000x reference)
//
#include <hip/hip_runtime.h>

#define LOG2E 1.4426950408889634f
#define LN2   0.6931471805599453f
#define NEGF  -1.0e30f

// 3-way logsumexp in base-2 log domain. Handles NEGF sentinels:
// all-NEGF -> m=-1e30, diffs=0 -> m + log2(3) ~= -1e30. No NaN/inf paths.
__device__ __forceinline__ float lse3(float x, float y, float z) {
    float m = fmaxf(fmaxf(x, y), z);
    float s = __builtin_amdgcn_exp2f(x - m)
            + __builtin_amdgcn_exp2f(y - m)
            + __builtin_amdgcn_exp2f(z - m);
    return m + __builtin_amdgcn_logf(s);   // v_log_f32 is log2
}

// Phase 1: per-(b,t) log-softmax normalizer, in log2 units.
// norm2[row] = max*log2e + log2(sum 2^((x-max)*log2e))
// One block per row of V=1000 floats (250 float4 loads by threads 0..249).
__global__ __launch_bounds__(256) void norm_kernel(const float* __restrict__ pred,
                                                   float* __restrict__ norm2,
                                                   int V) {
    int row = blockIdx.x;
    int tid = threadIdx.x;
    const float* rowp = pred + (size_t)row * V;
    float4 v = make_float4(-3.0e38f, -3.0e38f, -3.0e38f, -3.0e38f);
    int i4 = tid * 4;
    bool have = (i4 + 3 < V);           // V divisible by 4 in this problem
    if (have) v = *(const float4*)(rowp + i4);
    float lm = fmaxf(fmaxf(v.x, v.y), fmaxf(v.z, v.w));
    __shared__ float red[8];
    #pragma unroll
    for (int off = 32; off > 0; off >>= 1) lm = fmaxf(lm, __shfl_xor(lm, off));
    int wid = tid >> 6, lane = tid & 63;
    if (lane == 0) red[wid] = lm;
    __syncthreads();
    if (tid == 0) red[4] = fmaxf(fmaxf(red[0], red[1]), fmaxf(red[2], red[3]));
    __syncthreads();
    float mm = red[4] * LOG2E;          // max in log2 units
    float ls = 0.f;
    if (have) {
        ls = __builtin_amdgcn_exp2f(fmaf(v.x, LOG2E, -mm))
           + __builtin_amdgcn_exp2f(fmaf(v.y, LOG2E, -mm))
           + __builtin_amdgcn_exp2f(fmaf(v.z, LOG2E, -mm))
           + __builtin_amdgcn_exp2f(fmaf(v.w, LOG2E, -mm));
    }
    #pragma unroll
    for (int off = 32; off > 0; off >>= 1) ls += __shfl_xor(ls, off);
    if (lane == 0) red[wid] = ls;       // safe: red[0..3] reads all happened pre-2nd-sync
    __syncthreads();
    if (tid == 0) {
        float st = (red[0] + red[1]) + (red[2] + red[3]);
        norm2[row] = mm + __builtin_amdgcn_logf(st);
    }
}

// Phase 2: W-CTC forward DP, one block per batch sample, one thread per
// extended-label state (S = 2L+2 = 258 states; threads 258..319 are harmless
// padding — their values never flow into valid states since transitions only
// go s-2,s-1,s -> s and outputs read states ll=2*tl, lb=ll+1 only).
// Everything in base-2 log domain; alpha double-buffered in LDS with a +2
// front pad of NEGF so s-1/s-2 reads need no bounds checks.
__global__ __launch_bounds__(320) void dp_kernel(const float* __restrict__ pred,
                                                 const int* __restrict__ target,
                                                 const int* __restrict__ tlen,
                                                 const float* __restrict__ norm2,
                                                 float* __restrict__ nll,
                                                 int T, int V, int L) {
    int b = blockIdx.x;
    int s = threadIdx.x;
    __shared__ float A[2][324];   // [buf][state+2]; slots 0,1 are permanent NEGF pads
    __shared__ float fin[4];      // [0]=endstar part(ll) [1]=endstar part(lb) [2]=aT[ll] [3]=aT[lb]

    int tl = tlen[b];
    bool isLabel = (s >= 2) && ((s & 1) == 0);
    int l = isLabel ? ((s - 2) >> 1) : 0;
    if (l > L - 1) l = L - 1;
    int tok = isLabel ? target[b * L + l] : 0;   // blank=0 for star/blank states
    bool skip = false;
    if (isLabel) {
        int pl = (s - 4) >> 1;
        pl = pl < 0 ? 0 : (pl > L - 1 ? L - 1 : pl);
        skip = (s == 2) || (target[b * L + pl] != tok);
    }

    const float* prow = pred + (size_t)b * T * V;
    const float* nrow = norm2 + b * T;

    // t = 0 init
    float p_cur = prow[tok];
    float n_cur = nrow[0];
    float em0 = (s == 0) ? 0.f : fmaf(p_cur, LOG2E, -n_cur);
    float a = NEGF;
    if (s == 0) a = 0.f;
    else if (s == 1 || s == 2) a = em0;
    if (s > 2 * tl + 1) a = NEGF;   // init validity mask (matches reference)

    A[0][s + 2] = a;
    if (s < 2) { A[0][s] = NEGF; A[1][s] = NEGF; }

    // end-star running-lse state, kept only by the two threads owning ll/lb
    bool isEnd = (s == 2 * tl) || (s == 2 * tl + 1);
    float m_es = NEGF, s_es = 0.f;

    // prefetch t=1 emission inputs
    float p_nxt = prow[(size_t)V + tok];
    float n_nxt = nrow[1];
    __syncthreads();

    int cur = 0;
    for (int t = 1; t < T; ++t) {
        float pv = p_nxt, nv = n_nxt;
        int tn = (t + 1 < T) ? (t + 1) : (T - 1);
        p_nxt = prow[(size_t)tn * V + tok];   // prefetch next step's gather
        n_nxt = nrow[tn];

        float am1 = A[cur][s + 1];                  // alpha_{t-1}[s-1]
        float am2 = skip ? A[cur][s] : NEGF;        // alpha_{t-1}[s-2] if skip allowed

        if (isEnd) {  // endstar absorbs alpha_{t-1}[ll/lb] (pre-update value = register a)
            float mn = fmaxf(m_es, a);
            s_es = s_es * __builtin_amdgcn_exp2f(m_es - mn) + __builtin_amdgcn_exp2f(a - mn);
            m_es = mn;
        }

        float emt = (s == 0) ? 0.f : fmaf(pv, LOG2E, -nv);
        a = emt + lse3(a, am1, am2);
        A[cur ^ 1][s + 2] = a;
        cur ^= 1;
        __syncthreads();
    }

    if (isEnd) {
        int slot = s & 1;                      // ll even -> 0, lb -> 1
        fin[slot] = m_es + __builtin_amdgcn_logf(s_es);
        fin[2 + slot] = a;
    }
    __syncthreads();
    if (s == 0) {
        // endstar = lse2(partials), total = lse3(endstar, aT[ll], aT[lb])
        float es = fmaxf(fin[0], fin[1]);
        es = es + __builtin_amdgcn_logf(__builtin_amdgcn_exp2f(fin[0] - es)
                                      + __builtin_amdgcn_exp2f(fin[1] - es));
        float tot = lse3(es, fin[2], fin[3]);
        nll[b] = -(tot * LN2);                 // back to nats
    }
}

// Phase 3: out = mean_b( nll[b] / tlen[b] )
__global__ __launch_bounds__(64) void fin_kernel(const float* __restrict__ nll,
                                                 const int* __restrict__ tlen,
                                                 float* __restrict__ out, int B) {
    int tid = threadIdx.x;
    float v = (tid < B) ? nll[tid] / (float)tlen[tid] : 0.f;
    #pragma unroll
    for (int off = 32; off > 0; off >>= 1) v += __shfl_xor(v, off);
    if (tid == 0) out[0] = v / (float)B;
}

extern "C" void kernel_launch(void* const* d_in, const int* in_sizes, int n_in,
                              void* d_out, int out_size, void* d_ws, size_t ws_size,
                              hipStream_t stream) {
    const float* pred   = (const float*)d_in[0];
    const int*   target = (const int*)d_in[1];
    const int*   tlen   = (const int*)d_in[2];
    int B = in_sizes[2];
    int L = in_sizes[1] / B;
    int V = 1000;                       // fixed by the problem
    int T = in_sizes[0] / (B * V);

    float* ws    = (float*)d_ws;
    float* nll   = ws;                  // B floats
    float* norm2 = ws + 64;             // B*T floats (fully written by phase 1)

    norm_kernel<<<B * T, 256, 0, stream>>>(pred, norm2, V);
    dp_kernel<<<B, 320, 0, stream>>>(pred, target, tlen, norm2, nll, T, V, L);
    fin_kernel<<<1, 64, 0, stream>>>(nll, tlen, (float*)d_out, B);
}